// Round 14
// baseline (394.833 us; speedup 1.0000x reference)
//
#include <hip/hip_runtime.h>
#include <cstdint>

// MTNN: static MLP + dyn proj + biRNN(relu) + routed per-trial dot.
// B=512,T=200,SI=100,DI=68,HS=256,HD=128,D=512,K=1. fp32 in, fp32 out.
// R20 (244.5us, 5 launches): ~110us inter-launch overhead is the top cost.
// R22 (coop kernel): FAILED with absmax == max|ref| -> out never written ->
// hipLaunchCooperativeKernel launch itself failed (unchecked). grid.sync
// unproven; R21 however PROVED the hand-rolled pattern (stores ->
// syncthreads -> RELEASE fetch_add agent-scope / ACQUIRE load) works
// cross-XCD on this chip.
// R23: R22's phase plan with R21-proven hand-rolled grid barriers, ordinary
// launches. Launch1 k_prep_static (prep + static + zero counters).
// Launch2 k_fused, 256 blocks x 256 thr, launch_bounds(256,1) -> 1
// block/CU by capacity (all co-resident -> spin barrier safe; bounded spin
// -> no hang):
//   P1 R20 persistent dxw VERBATIM (hoisted weights, b-major tiles)
//   barrier A -> P2 blocks 0..63: R17 4-wave scan (per-wave acc slices)
//   barrier B -> P3 final (statd + 4+4 partials).
constexpr int B = 512, T = 200, SI = 100, DI = 68, HS = 256, HD = 128, D = 512;
constexpr int BT = B * T;       // 102400
constexpr int NT = BT / 64;     // 1600 tiles (b-major)

typedef __attribute__((ext_vector_type(8))) short short8;       // 8 bf16
typedef __attribute__((ext_vector_type(4))) float floatx4;      // MFMA C/D
typedef _Float16 half8 __attribute__((ext_vector_type(8)));     // 8 fp16
typedef _Float16 half2t __attribute__((ext_vector_type(2)));    // fp16 pair
typedef unsigned int uint2v __attribute__((ext_vector_type(2)));
typedef unsigned int uint4v __attribute__((ext_vector_type(4)));

#define DEV __device__ __forceinline__

DEV unsigned short f2bf(float f) {
    unsigned int x = __builtin_bit_cast(unsigned int, f);
    x += 0x7fffu + ((x >> 16) & 1u);   // RNE
    return (unsigned short)(x >> 16);
}
DEV unsigned int pkbf(float a, float b) {
    return (unsigned int)f2bf(a) | ((unsigned int)f2bf(b) << 16);
}
DEV unsigned short f2h(float f) {
    return __builtin_bit_cast(unsigned short, (_Float16)f);
}
DEV half2t u2h2(unsigned int u) { return __builtin_bit_cast(half2t, u); }
DEV unsigned int pkh(float a, float b) {
    return __builtin_bit_cast(unsigned int, __builtin_amdgcn_cvt_pkrtz(a, b));
}
#if __has_builtin(__builtin_amdgcn_permlane32_swap) && __has_builtin(__builtin_amdgcn_permlane16_swap)
DEV void pl32swap(unsigned int& a, unsigned int& b) {
    uint2v r = __builtin_amdgcn_permlane32_swap(a, b, false, false);
    a = r[0]; b = r[1];
}
DEV void pl16swap(unsigned int& a, unsigned int& b) {
    uint2v r = __builtin_amdgcn_permlane16_swap(a, b, false, false);
    a = r[0]; b = r[1];
}
#else
DEV void pl32swap(unsigned int& a, unsigned int& b) {
    unsigned int na, nb;
    asm("v_mov_b32 %0, %2\n\t"
        "v_mov_b32 %1, %3\n\t"
        "v_permlane32_swap_b32 %0, %1"
        : "=&v"(na), "=&v"(nb) : "v"(a), "v"(b));
    a = na; b = nb;
}
DEV void pl16swap(unsigned int& a, unsigned int& b) {
    unsigned int na, nb;
    asm("v_mov_b32 %0, %2\n\t"
        "v_mov_b32 %1, %3\n\t"
        "v_permlane16_swap_b32 %0, %1"
        : "=&v"(na), "=&v"(nb) : "v"(a), "v"(b));
    a = na; b = nb;
}
#endif

// hand-rolled grid barrier (R21-proven semantics). All 256 blocks
// co-resident by capacity; bounded spin -> wrong-answer not hang on bug.
DEV void gbar(int* cnt) {
    __syncthreads();   // intra-block + drains vmcnt/lgkm (stores complete)
    if (threadIdx.x == 0) {
        __hip_atomic_fetch_add(cnt, 1, __ATOMIC_RELEASE,
                               __HIP_MEMORY_SCOPE_AGENT);
        for (long it = 0; it < (1L << 24); ++it) {
            if (__hip_atomic_load(cnt, __ATOMIC_ACQUIRE,
                                  __HIP_MEMORY_SCOPE_AGENT) >= 256) break;
            __builtin_amdgcn_s_sleep(8);
        }
    }
    __syncthreads();
}

// ---------------- K0: prep + static branch + zero counters ------------------
__global__ __launch_bounds__(256) void k_prep_static(
    const float* __restrict__ wdyn,
    const float* __restrict__ wihf, const float* __restrict__ wihb,
    const float* __restrict__ whhf, const float* __restrict__ whhb,
    const float* __restrict__ bihf, const float* __restrict__ bhhf,
    const float* __restrict__ bihb, const float* __restrict__ bhhb,
    unsigned short* __restrict__ wdyn_bf, unsigned short* __restrict__ wih_bf,
    unsigned short* __restrict__ whh_h, float* __restrict__ bsum,
    const float* __restrict__ xs_g, const float* __restrict__ w1,
    const float* __restrict__ b1, const float* __restrict__ w2,
    const float* __restrict__ b2, const int* __restrict__ norder,
    const float* __restrict__ nw, const float* __restrict__ nb,
    float* __restrict__ statd, int* __restrict__ cnts)
{
    int tid = threadIdx.x;
    int gid = blockIdx.x * 256 + tid, gs = gridDim.x * 256;
    // prep (grid-stride over all 512 blocks)
    for (int i = gid; i < HD * 96; i += gs) {
        int r = i / 96, c = i - r * 96;
        wdyn_bf[i] = (c < DI) ? f2bf(wdyn[r * DI + c]) : 0;
    }
    for (int i = gid; i < 2 * HD * HD; i += gs) {
        const float* src = (i < HD * HD) ? wihf : wihb;
        wih_bf[i] = f2bf(src[i & (HD * HD - 1)]);
    }
    for (int i = gid; i < 2 * HD * HD; i += gs) {
        const float* src = (i < HD * HD) ? whhf : whhb;
        whh_h[i] = f2h(src[i & (HD * HD - 1)]);
    }
    for (int i = gid; i < 2 * HD; i += gs) {
        int z = i >> 7, n = i & (HD - 1);
        bsum[i] = z ? (bihb[n] + bhhb[n]) : (bihf[n] + bhhf[n]);
    }
    if (gid < 2) cnts[gid] = 0;

    // static branch: b = blockIdx.x (512 blocks)
    __shared__ __align__(16) float sxs[104];
    __shared__ __align__(16) float ss1[HS];
    __shared__ __align__(16) float sred[256];
    int b = blockIdx.x;
    if (tid < SI) sxs[tid] = xs_g[b * SI + tid];
    __syncthreads();
    float a = b1[tid];
    const float4* wr  = (const float4*)(w1 + tid * SI);
    const float4* xp4 = (const float4*)sxs;
    #pragma unroll
    for (int i = 0; i < SI / 4; ++i) {
        float4 ww = wr[i]; float4 xx = xp4[i];
        a += xx.x * ww.x + xx.y * ww.y + xx.z * ww.z + xx.w * ww.w;
    }
    ss1[tid] = fmaxf(a, 0.f);
    __syncthreads();
    float a2 = b2[tid];
    const float4* w2p = (const float4*)(w2 + tid * HS);
    const float4* s1p = (const float4*)ss1;
    #pragma unroll 8
    for (int i = 0; i < HS / 4; ++i) {
        float4 ww = w2p[i]; float4 s = s1p[i];
        a2 += s.x * ww.x + s.y * ww.y + s.z * ww.z + s.w * ww.w;
    }
    float sv = fmaxf(a2, 0.f);
    int n = norder[b];
    sred[tid] = sv * nw[(size_t)n * D + tid];
    __syncthreads();
    for (int s = 128; s > 0; s >>= 1) {
        if (tid < s) sred[tid] += sred[tid + s];
        __syncthreads();
    }
    if (tid == 0) statd[b] = sred[0] + nb[n];
}

// ---------------- K1: fused dxw -> barrier -> scan -> barrier -> final ------
__global__ __launch_bounds__(256, 1) void k_fused(
    const float* __restrict__ xd,
    const unsigned short* __restrict__ wdyn_bf, const float* __restrict__ bdyn,
    const unsigned short* __restrict__ wih_bf, const float* __restrict__ bsum,
    unsigned short* __restrict__ xw, const unsigned short* __restrict__ whh_h,
    const int* __restrict__ norder, const float* __restrict__ nw,
    float* __restrict__ accf, float* __restrict__ accb,
    const float* __restrict__ statd, float* __restrict__ out,
    int* __restrict__ cnts)
{
    __shared__ __align__(16) unsigned char smem[30720];
    int tid = threadIdx.x;
    int lane = tid & 63, wv = tid >> 6, ln = lane & 15, q = lane >> 4;

    // =================== P1: persistent dxw (R20 verbatim) ==================
    {
        unsigned short (*xb)[104] = (unsigned short(*)[104])smem;           // 13312B
        unsigned short (*dl)[136] = (unsigned short(*)[136])(smem + 13312); // 17408B

        short8 wdf[8][3];        // wdyn frags: 96 VGPR
        #pragma unroll
        for (int j = 0; j < 8; ++j)
            #pragma unroll
            for (int c = 0; c < 3; ++c)
                wdf[j][c] = *(const short8*)(wdyn_bf + (size_t)(j * 16 + ln) * 96 + c * 32 + q * 8);
        short8 wif[2][8][4];     // wih frags both dirs: 256 VGPR
        #pragma unroll
        for (int z = 0; z < 2; ++z)
            #pragma unroll
            for (int j = 0; j < 8; ++j)
                #pragma unroll
                for (int c = 0; c < 4; ++c)
                    wif[z][j][c] = *(const short8*)(wih_bf + (size_t)z * HD * HD +
                        (size_t)(j * 16 + ln) * HD + c * 32 + q * 8);

        for (int i = tid; i < 64 * 104 / 8; i += 256)
            ((uint4v*)xb)[i] = uint4v{0u, 0u, 0u, 0u};
        __syncthreads();

        auto stage = [&](int tile) {
            int R0 = tile * 64;
            for (int i = tid; i < 64 * 17; i += 256) {
                int r = i / 17, c = i - r * 17;
                float4 v = *(const float4*)(xd + (size_t)(R0 + r) * DI + c * 4);
                uint2 pk;
                pk.x = pkbf(v.x, v.y);
                pk.y = pkbf(v.z, v.w);
                *(uint2*)&xb[r][c * 4] = pk;
            }
        };

        stage(blockIdx.x);
        __syncthreads();

        for (int tile = blockIdx.x; tile < NT; tile += gridDim.x) {
            int R0 = tile * 64;
            short8 xf[3];
            #pragma unroll
            for (int c = 0; c < 3; ++c)
                xf[c] = *(const short8*)&xb[wv * 16 + ln][c * 32 + q * 8];
            #pragma unroll
            for (int j = 0; j < 8; ++j) {
                floatx4 a = {0.f, 0.f, 0.f, 0.f};
                #pragma unroll
                for (int c = 0; c < 3; ++c)
                    a = __builtin_amdgcn_mfma_f32_16x16x32_bf16(wdf[j][c], xf[c], a, 0, 0, 0);
                float4 bd4 = *(const float4*)(bdyn + j * 16 + q * 4);
                uint2 pk;
                pk.x = pkbf(fmaxf(a[0] + bd4.x, 0.f), fmaxf(a[1] + bd4.y, 0.f));
                pk.y = pkbf(fmaxf(a[2] + bd4.z, 0.f), fmaxf(a[3] + bd4.w, 0.f));
                *(uint2*)&dl[wv * 16 + ln][j * 16 + q * 4] = pk;
            }
            __syncthreads();

            int nxt = tile + gridDim.x;
            if (nxt < NT) stage(nxt);
            short8 df[4];
            #pragma unroll
            for (int c = 0; c < 4; ++c)
                df[c] = *(const short8*)&dl[wv * 16 + ln][c * 32 + q * 8];
            int row = R0 + wv * 16 + ln;
            #pragma unroll
            for (int z = 0; z < 2; ++z) {
                unsigned short* outp = xw + (size_t)z * BT * HD;
                #pragma unroll
                for (int j = 0; j < 8; ++j) {
                    floatx4 a = {0.f, 0.f, 0.f, 0.f};
                    #pragma unroll
                    for (int c = 0; c < 4; ++c)
                        a = __builtin_amdgcn_mfma_f32_16x16x32_bf16(wif[z][j][c], df[c], a, 0, 0, 0);
                    float4 b4 = *(const float4*)(bsum + z * HD + j * 16 + q * 4);
                    uint2 hp;
                    hp.x = (unsigned int)f2h(a[0] + b4.x) | ((unsigned int)f2h(a[1] + b4.y) << 16);
                    hp.y = (unsigned int)f2h(a[2] + b4.z) | ((unsigned int)f2h(a[3] + b4.w) << 16);
                    *(uint2*)(outp + (size_t)row * HD + j * 16 + q * 4) = hp;
                }
            }
            __syncthreads();
        }
    }

    gbar(&cnts[0]);   // all xw visible device-wide (R21-proven pattern)

    // =================== P2: scan, blocks 0..63 (R17 4-wave) ================
    if (blockIdx.x < 64) {
        uint4v (*hxch)[4][64] = (uint4v(*)[4][64])smem;   // 8192B

        int g = blockIdx.x;
        int dirv = g >> 5, b0 = (g & 31) * 16;
        const unsigned short* whh = whh_h + (size_t)dirv * HD * HD;
        float* accp = (dirv ? accb : accf) + (size_t)wv * BT + (size_t)(b0 + ln) * T;
        int segoff = dirv ? (HS + HD) : HS;
        int j0 = 2 * wv;

        half8 wfr[2][4];
        #pragma unroll
        for (int jj = 0; jj < 2; ++jj)
            #pragma unroll
            for (int c = 0; c < 4; ++c)
                wfr[jj][c] = *(const half8*)(whh + (size_t)((j0 + jj) * 16 + ln) * HD + c * 32 + q * 8);

        int nrow = norder[b0 + ln];
        float4 wnl[2];
        #pragma unroll
        for (int jj = 0; jj < 2; ++jj)
            wnl[jj] = *(const float4*)(nw + (size_t)nrow * D + segoff + (j0 + jj) * 16 + q * 4);

        half8 hf[4];
        uint4v zz = {0u, 0u, 0u, 0u};
        #pragma unroll
        for (int c = 0; c < 4; ++c) hf[c] = __builtin_bit_cast(half8, zz);

        const unsigned short* xp = xw + ((size_t)dirv * BT + (size_t)(b0 + ln) * T) * HD;
        int tstart = dirv ? (T - 1) : 0, dt = dirv ? -1 : 1;

        uint2 x0[2], x1[2], x2[2], x3[2];
        auto ld = [&](uint2 (&xc)[2], int idx) {
            const unsigned short* pp = xp + (size_t)(tstart + dt * idx) * HD;
            #pragma unroll
            for (int jj = 0; jj < 2; ++jj)
                xc[jj] = *(const uint2*)(pp + (j0 + jj) * 16 + q * 4);
        };
        auto step = [&](uint2 (&xc)[2], int idx) {
            int t = tstart + dt * idx;
            int par = idx & 1;
            floatx4 a[2];
            #pragma unroll
            for (int jj = 0; jj < 2; ++jj) {
                half2t lo = u2h2(xc[jj].x), hi = u2h2(xc[jj].y);
                a[jj] = floatx4{(float)lo[0], (float)lo[1], (float)hi[0], (float)hi[1]};
            }
            #pragma unroll
            for (int cc = 0; cc < 4; ++cc)
                #pragma unroll
                for (int jj = 0; jj < 2; ++jj)
                    a[jj] = __builtin_amdgcn_mfma_f32_16x16x32_f16(wfr[jj][cc], hf[cc], a[jj], 0, 0, 0);
            uint2 hp[2];
            float pdot = 0.f;
            #pragma unroll
            for (int jj = 0; jj < 2; ++jj) {
                float r0 = fmaxf(a[jj][0], 0.f), r1 = fmaxf(a[jj][1], 0.f);
                float r2 = fmaxf(a[jj][2], 0.f), r3 = fmaxf(a[jj][3], 0.f);
                hp[jj].x = pkh(r0, r1);
                hp[jj].y = pkh(r2, r3);
                float4 wn4 = wnl[jj];
                pdot += r0 * wn4.x + r1 * wn4.y + r2 * wn4.z + r3 * wn4.w;
            }
            unsigned int ax = hp[0].x, bx = hp[1].x;
            pl32swap(ax, bx); pl16swap(ax, bx);
            unsigned int ay = hp[0].y, by = hp[1].y;
            pl32swap(ay, by); pl16swap(ay, by);
            hxch[par][wv][lane] = uint4v{ax, ay, bx, by};
            unsigned int pa = __builtin_bit_cast(unsigned int, pdot), pb = pa;
            pl32swap(pa, pb);
            float ps = __builtin_bit_cast(float, pa) + __builtin_bit_cast(float, pb);
            unsigned int pc = __builtin_bit_cast(unsigned int, ps), pd = pc;
            pl16swap(pc, pd);
            float ptot = __builtin_bit_cast(float, pc) + __builtin_bit_cast(float, pd);
            if (lane < 16) accp[t] = ptot;
            asm volatile("s_waitcnt lgkmcnt(0)" ::: "memory");
            __builtin_amdgcn_sched_barrier(0);
            __builtin_amdgcn_s_barrier();
            __builtin_amdgcn_sched_barrier(0);
            #pragma unroll
            for (int c = 0; c < 4; ++c)
                hf[c] = __builtin_bit_cast(half8, hxch[par][c][lane]);
        };

        ld(x0, 0); ld(x1, 1); ld(x2, 2); ld(x3, 3);
        for (int c = 0; c < T / 4 - 1; ++c) {
            int i0 = c * 4;
            step(x0, i0);     ld(x0, i0 + 4);
            step(x1, i0 + 1); ld(x1, i0 + 5);
            step(x2, i0 + 2); ld(x2, i0 + 6);
            step(x3, i0 + 3); ld(x3, i0 + 7);
        }
        step(x0, T - 4);
        step(x1, T - 3);
        step(x2, T - 2);
        step(x3, T - 1);
    }

    gbar(&cnts[1]);   // all acc partials visible

    // =================== P3: final ==========================================
    for (int idx = blockIdx.x * 256 + tid; idx < BT; idx += gridDim.x * 256) {
        int b = idx / T;
        float s = statd[b];
        #pragma unroll
        for (int w = 0; w < 4; ++w)
            s += accf[(size_t)w * BT + idx] + accb[(size_t)w * BT + idx];
        out[idx] = fmaxf(s, 0.f);
    }
}

extern "C" void kernel_launch(void* const* d_in, const int* in_sizes, int n_in,
                              void* d_out, int out_size, void* d_ws, size_t ws_size,
                              hipStream_t stream)
{
    const float* x_static  = (const float*)d_in[0];
    const float* x_dynamic = (const float*)d_in[1];
    const int*   norder    = (const int*)d_in[2];
    const float* w_s1   = (const float*)d_in[3];
    const float* b_s1   = (const float*)d_in[4];
    const float* w_s2   = (const float*)d_in[5];
    const float* b_s2   = (const float*)d_in[6];
    const float* w_dyn  = (const float*)d_in[7];
    const float* b_dyn  = (const float*)d_in[8];
    const float* w_ih_f = (const float*)d_in[9];
    const float* w_hh_f = (const float*)d_in[10];
    const float* b_ih_f = (const float*)d_in[11];
    const float* b_hh_f = (const float*)d_in[12];
    const float* w_ih_b = (const float*)d_in[13];
    const float* w_hh_b = (const float*)d_in[14];
    const float* b_ih_b = (const float*)d_in[15];
    const float* b_hh_b = (const float*)d_in[16];
    const float* nw     = (const float*)d_in[17];
    const float* nb     = (const float*)d_in[18];
    float* out = (float*)d_out;

    // ws: statd 2KB | accf 4*BT*4 | accb 4*BT*4 | xw 52.4MB | wts | counters
    char* ws = (char*)d_ws;
    float* statd = (float*)ws;
    float* accf  = (float*)(ws + 2048);
    float* accb  = (float*)(ws + 2048 + (size_t)4 * BT * 4);
    unsigned short* xw = (unsigned short*)(ws + 2048 + (size_t)8 * BT * 4);
    size_t xw_bytes = (size_t)2 * BT * HD * 2;   // 52.4 MB
    unsigned short* wdyn_bf = (unsigned short*)(ws + 2048 + (size_t)8 * BT * 4 + xw_bytes);
    unsigned short* wih_bf  = wdyn_bf + HD * 96;
    unsigned short* whh_h   = wih_bf + 2 * HD * HD;
    float* bsum = (float*)(whh_h + 2 * HD * HD);
    int*   cnts = (int*)(bsum + 2 * HD);

    hipLaunchKernelGGL(k_prep_static, dim3(512), dim3(256), 0, stream,
                       w_dyn, w_ih_f, w_ih_b, w_hh_f, w_hh_b,
                       b_ih_f, b_hh_f, b_ih_b, b_hh_b,
                       wdyn_bf, wih_bf, whh_h, bsum,
                       x_static, w_s1, b_s1, w_s2, b_s2, norder, nw, nb,
                       statd, cnts);
    hipLaunchKernelGGL(k_fused, dim3(256), dim3(256), 0, stream,
                       x_dynamic, wdyn_bf, b_dyn, wih_bf, bsum,
                       xw, whh_h, norder, nw, accf, accb, statd, out, cnts);
}

// Round 15
// 316.819 us; speedup vs baseline: 1.2462x; 1.2462x over previous
//
#include <hip/hip_runtime.h>
#include <cstdint>

// MTNN: static MLP + dyn proj + biRNN(relu) + routed per-trial dot.
// B=512,T=200,SI=100,DI=68,HS=256,HD=128,D=512,K=1. fp32 in, fp32 out.
// R20 (244.5us, BEST): 5 launches, ~110us launch overhead.
// R21-R23 (fusion arc): producer/consumer + coop + hand-rolled barrier all
// lost -- fused kernels break dxw weight hoisting (R23: VGPR 248, dxw phase
// ~185us at 4 waves/CU). Mega-kernel abandoned.
// R24: launch consolidation with NO new sync mechanisms:
//  L1 k_prep_static (merged independent work, 512 blocks; R23-proven).
//  L2 k_dxw = R20 VERBATIM (standalone -> regalloc unperturbed).
//  L3 k_scan_final: 32 blocks x 1024 thr (16 waves): waves 0-7 fwd scan
//     (R19 8-wave structure verbatim), waves 8-15 bwd, same 16 b-rows.
//     s_barrier spans both dir-groups (symmetric -> lockstep ~free);
//     per-dir handoff LDS. Both dirs' partials in ONE block -> final sum
//     in-block after the loop (L2-hot) -> k_final launch deleted.
// 5 launches -> 3 (~44us of gaps + k_final removed).
constexpr int B = 512, T = 200, SI = 100, DI = 68, HS = 256, HD = 128, D = 512;
constexpr int BT = B * T;       // 102400
constexpr int NT = BT / 64;     // 1600 tiles (b-major)

typedef __attribute__((ext_vector_type(8))) short short8;       // 8 bf16
typedef __attribute__((ext_vector_type(4))) float floatx4;      // MFMA C/D
typedef _Float16 half8 __attribute__((ext_vector_type(8)));     // 8 fp16
typedef _Float16 half2t __attribute__((ext_vector_type(2)));    // fp16 pair
typedef unsigned int uint2v __attribute__((ext_vector_type(2)));
typedef unsigned int uint4v __attribute__((ext_vector_type(4)));

#define DEV __device__ __forceinline__

DEV unsigned short f2bf(float f) {
    unsigned int x = __builtin_bit_cast(unsigned int, f);
    x += 0x7fffu + ((x >> 16) & 1u);   // RNE
    return (unsigned short)(x >> 16);
}
DEV unsigned int pkbf(float a, float b) {
    return (unsigned int)f2bf(a) | ((unsigned int)f2bf(b) << 16);
}
DEV unsigned short f2h(float f) {
    return __builtin_bit_cast(unsigned short, (_Float16)f);
}
DEV half2t u2h2(unsigned int u) { return __builtin_bit_cast(half2t, u); }
DEV unsigned int pkh(float a, float b) {
    return __builtin_bit_cast(unsigned int, __builtin_amdgcn_cvt_pkrtz(a, b));
}
#if __has_builtin(__builtin_amdgcn_permlane32_swap) && __has_builtin(__builtin_amdgcn_permlane16_swap)
DEV void pl32swap(unsigned int& a, unsigned int& b) {
    uint2v r = __builtin_amdgcn_permlane32_swap(a, b, false, false);
    a = r[0]; b = r[1];
}
DEV void pl16swap(unsigned int& a, unsigned int& b) {
    uint2v r = __builtin_amdgcn_permlane16_swap(a, b, false, false);
    a = r[0]; b = r[1];
}
#else
DEV void pl32swap(unsigned int& a, unsigned int& b) {
    unsigned int na, nb;
    asm("v_mov_b32 %0, %2\n\t"
        "v_mov_b32 %1, %3\n\t"
        "v_permlane32_swap_b32 %0, %1"
        : "=&v"(na), "=&v"(nb) : "v"(a), "v"(b));
    a = na; b = nb;
}
DEV void pl16swap(unsigned int& a, unsigned int& b) {
    unsigned int na, nb;
    asm("v_mov_b32 %0, %2\n\t"
        "v_mov_b32 %1, %3\n\t"
        "v_permlane16_swap_b32 %0, %1"
        : "=&v"(na), "=&v"(nb) : "v"(a), "v"(b));
    a = na; b = nb;
}
#endif

// ---------------- K0: prep + static branch (merged, independent) ------------
__global__ __launch_bounds__(256) void k_prep_static(
    const float* __restrict__ wdyn,
    const float* __restrict__ wihf, const float* __restrict__ wihb,
    const float* __restrict__ whhf, const float* __restrict__ whhb,
    const float* __restrict__ bihf, const float* __restrict__ bhhf,
    const float* __restrict__ bihb, const float* __restrict__ bhhb,
    unsigned short* __restrict__ wdyn_bf, unsigned short* __restrict__ wih_bf,
    unsigned short* __restrict__ whh_h, float* __restrict__ bsum,
    const float* __restrict__ xs_g, const float* __restrict__ w1,
    const float* __restrict__ b1, const float* __restrict__ w2,
    const float* __restrict__ b2, const int* __restrict__ norder,
    const float* __restrict__ nw, const float* __restrict__ nb,
    float* __restrict__ statd)
{
    int tid = threadIdx.x;
    int gid = blockIdx.x * 256 + tid, gs = gridDim.x * 256;
    // prep (grid-stride over all 512 blocks)
    for (int i = gid; i < HD * 96; i += gs) {
        int r = i / 96, c = i - r * 96;
        wdyn_bf[i] = (c < DI) ? f2bf(wdyn[r * DI + c]) : 0;
    }
    for (int i = gid; i < 2 * HD * HD; i += gs) {
        const float* src = (i < HD * HD) ? wihf : wihb;
        wih_bf[i] = f2bf(src[i & (HD * HD - 1)]);
    }
    for (int i = gid; i < 2 * HD * HD; i += gs) {
        const float* src = (i < HD * HD) ? whhf : whhb;
        whh_h[i] = f2h(src[i & (HD * HD - 1)]);
    }
    for (int i = gid; i < 2 * HD; i += gs) {
        int z = i >> 7, n = i & (HD - 1);
        bsum[i] = z ? (bihb[n] + bhhb[n]) : (bihf[n] + bhhf[n]);
    }

    // static branch: b = blockIdx.x (512 blocks)
    __shared__ __align__(16) float sxs[104];
    __shared__ __align__(16) float ss1[HS];
    __shared__ __align__(16) float sred[256];
    int b = blockIdx.x;
    if (tid < SI) sxs[tid] = xs_g[b * SI + tid];
    __syncthreads();
    float a = b1[tid];
    const float4* wr  = (const float4*)(w1 + tid * SI);
    const float4* xp4 = (const float4*)sxs;
    #pragma unroll
    for (int i = 0; i < SI / 4; ++i) {
        float4 ww = wr[i]; float4 xx = xp4[i];
        a += xx.x * ww.x + xx.y * ww.y + xx.z * ww.z + xx.w * ww.w;
    }
    ss1[tid] = fmaxf(a, 0.f);
    __syncthreads();
    float a2 = b2[tid];
    const float4* w2p = (const float4*)(w2 + tid * HS);
    const float4* s1p = (const float4*)ss1;
    #pragma unroll 8
    for (int i = 0; i < HS / 4; ++i) {
        float4 ww = w2p[i]; float4 s = s1p[i];
        a2 += s.x * ww.x + s.y * ww.y + s.z * ww.z + s.w * ww.w;
    }
    float sv = fmaxf(a2, 0.f);
    int n = norder[b];
    sred[tid] = sv * nw[(size_t)n * D + tid];
    __syncthreads();
    for (int s = 128; s > 0; s >>= 1) {
        if (tid < s) sred[tid] += sred[tid + s];
        __syncthreads();
    }
    if (tid == 0) statd[b] = sred[0] + nb[n];
}

// ---------------- K1: persistent d + ih-projection (R20 verbatim) -----------
__global__ __launch_bounds__(256, 1) void k_dxw(
    const float* __restrict__ xd,
    const unsigned short* __restrict__ wdyn_bf, const float* __restrict__ bdyn,
    const unsigned short* __restrict__ wih_bf, const float* __restrict__ bsum,
    unsigned short* __restrict__ xw)
{
    __shared__ __align__(16) unsigned short xb[64][104];
    __shared__ __align__(16) unsigned short dl[64][136];
    int tid = threadIdx.x;
    int lane = tid & 63, w = tid >> 6;
    int ln = lane & 15, q = lane >> 4;

    short8 wdf[8][3];
    #pragma unroll
    for (int j = 0; j < 8; ++j)
        #pragma unroll
        for (int c = 0; c < 3; ++c)
            wdf[j][c] = *(const short8*)(wdyn_bf + (size_t)(j * 16 + ln) * 96 + c * 32 + q * 8);
    short8 wif[2][8][4];
    #pragma unroll
    for (int z = 0; z < 2; ++z)
        #pragma unroll
        for (int j = 0; j < 8; ++j)
            #pragma unroll
            for (int c = 0; c < 4; ++c)
                wif[z][j][c] = *(const short8*)(wih_bf + (size_t)z * HD * HD +
                    (size_t)(j * 16 + ln) * HD + c * 32 + q * 8);

    for (int i = tid; i < 64 * 104 / 8; i += 256)
        ((uint4v*)xb)[i] = uint4v{0u, 0u, 0u, 0u};

    auto stage = [&](int tile) {
        int R0 = tile * 64;
        for (int i = tid; i < 64 * 17; i += 256) {
            int r = i / 17, c = i - r * 17;
            float4 v = *(const float4*)(xd + (size_t)(R0 + r) * DI + c * 4);
            uint2 pk;
            pk.x = pkbf(v.x, v.y);
            pk.y = pkbf(v.z, v.w);
            *(uint2*)&xb[r][c * 4] = pk;
        }
    };

    stage(blockIdx.x);
    __syncthreads();

    for (int tile = blockIdx.x; tile < NT; tile += gridDim.x) {
        int R0 = tile * 64;
        short8 xf[3];
        #pragma unroll
        for (int c = 0; c < 3; ++c)
            xf[c] = *(const short8*)&xb[w * 16 + ln][c * 32 + q * 8];
        #pragma unroll
        for (int j = 0; j < 8; ++j) {
            floatx4 a = {0.f, 0.f, 0.f, 0.f};
            #pragma unroll
            for (int c = 0; c < 3; ++c)
                a = __builtin_amdgcn_mfma_f32_16x16x32_bf16(wdf[j][c], xf[c], a, 0, 0, 0);
            float4 bd4 = *(const float4*)(bdyn + j * 16 + q * 4);
            uint2 pk;
            pk.x = pkbf(fmaxf(a[0] + bd4.x, 0.f), fmaxf(a[1] + bd4.y, 0.f));
            pk.y = pkbf(fmaxf(a[2] + bd4.z, 0.f), fmaxf(a[3] + bd4.w, 0.f));
            *(uint2*)&dl[w * 16 + ln][j * 16 + q * 4] = pk;
        }
        __syncthreads();

        int nxt = tile + gridDim.x;
        if (nxt < NT) stage(nxt);
        short8 df[4];
        #pragma unroll
        for (int c = 0; c < 4; ++c)
            df[c] = *(const short8*)&dl[w * 16 + ln][c * 32 + q * 8];
        int row = R0 + w * 16 + ln;
        #pragma unroll
        for (int z = 0; z < 2; ++z) {
            unsigned short* outp = xw + (size_t)z * BT * HD;
            #pragma unroll
            for (int j = 0; j < 8; ++j) {
                floatx4 a = {0.f, 0.f, 0.f, 0.f};
                #pragma unroll
                for (int c = 0; c < 4; ++c)
                    a = __builtin_amdgcn_mfma_f32_16x16x32_bf16(wif[z][j][c], df[c], a, 0, 0, 0);
                float4 b4 = *(const float4*)(bsum + z * HD + j * 16 + q * 4);
                uint2 hp;
                hp.x = (unsigned int)f2h(a[0] + b4.x) | ((unsigned int)f2h(a[1] + b4.y) << 16);
                hp.y = (unsigned int)f2h(a[2] + b4.z) | ((unsigned int)f2h(a[3] + b4.w) << 16);
                *(uint2*)(outp + (size_t)row * HD + j * 16 + q * 4) = hp;
            }
        }
        __syncthreads();
    }
}

// ---------------- K2: scan both dirs (16 waves) + in-block final ------------
// 32 blocks x 1024 thr. Block g owns b = g*16..g*16+15, BOTH directions:
// waves 0-7 = fwd (R19 8-wave o-split verbatim), waves 8-15 = bwd.
// s_barrier spans both dir-groups (symmetric work -> lockstep ~free).
// After the loop: block sums statd + 8+8 partials -> out (L2-hot).
__global__ __launch_bounds__(1024, 1) void k_scan_final(
    const unsigned short* __restrict__ xw, const unsigned short* __restrict__ whh_h,
    const int* __restrict__ norder, const float* __restrict__ nw,
    float* __restrict__ accf, float* __restrict__ accb,
    const float* __restrict__ statd, float* __restrict__ out)
{
    __shared__ __align__(16) uint4v hxch[2][2][4][64];  // [dir][parity][chunk][lane]

    int tid = threadIdx.x;
    int wvall = tid >> 6;          // 0..15
    int dir = wvall >> 3;          // 0..1
    int wv = wvall & 7;            // o-tile index within dir
    int l = tid & 63, ln = l & 15, q = l >> 4;
    int b0 = blockIdx.x * 16;      // 32 blocks

    const unsigned short* whh = whh_h + (size_t)dir * HD * HD;
    float* accp = (dir ? accb : accf) + (size_t)wv * BT + (size_t)(b0 + ln) * T;
    int segoff = dir ? (HS + HD) : HS;

    // A-frags: Whh[o = wv*16+ln][k = c*32+q*8 .. +7], fp16
    half8 wfr[4];
    #pragma unroll
    for (int c = 0; c < 4; ++c)
        wfr[c] = *(const half8*)(whh + (size_t)(wv * 16 + ln) * HD + c * 32 + q * 8);

    int nrow = norder[b0 + ln];
    float4 wnl = *(const float4*)(nw + (size_t)nrow * D + segoff + wv * 16 + q * 4);

    half8 hf[4];
    uint4v zz = {0u, 0u, 0u, 0u};
    #pragma unroll
    for (int c = 0; c < 4; ++c) hf[c] = __builtin_bit_cast(half8, zz);

    const unsigned short* xp = xw + ((size_t)dir * BT + (size_t)(b0 + ln) * T) * HD
                               + wv * 16 + q * 4;
    int tstart = dir ? (T - 1) : 0, dt = dir ? -1 : 1;

    // handoff write slot (R19 math): chunk wc, quadrant qp, byte offset
    int wc = wv >> 1;
    int qp = 2 * (wv & 1) + (q >> 1);
    int boff = (q & 1) * 8;

    uint2 x0, x1, x2, x3;
    auto ld = [&](uint2& xb, int idx) {
        xb = *(const uint2*)(xp + (size_t)(tstart + dt * idx) * HD);
    };
    auto step = [&](uint2& xc, int idx) {
        int t = tstart + dt * idx;
        int par = idx & 1;
        half2t lo = u2h2(xc.x), hi = u2h2(xc.y);
        floatx4 a0 = {(float)lo[0], (float)lo[1], (float)hi[0], (float)hi[1]};
        floatx4 a1 = {0.f, 0.f, 0.f, 0.f};
        a0 = __builtin_amdgcn_mfma_f32_16x16x32_f16(wfr[0], hf[0], a0, 0, 0, 0);
        a1 = __builtin_amdgcn_mfma_f32_16x16x32_f16(wfr[1], hf[1], a1, 0, 0, 0);
        a0 = __builtin_amdgcn_mfma_f32_16x16x32_f16(wfr[2], hf[2], a0, 0, 0, 0);
        a1 = __builtin_amdgcn_mfma_f32_16x16x32_f16(wfr[3], hf[3], a1, 0, 0, 0);
        floatx4 a = a0 + a1;
        float r0 = fmaxf(a[0], 0.f), r1 = fmaxf(a[1], 0.f);
        float r2 = fmaxf(a[2], 0.f), r3 = fmaxf(a[3], 0.f);
        uint2 hp;
        hp.x = pkh(r0, r1);
        hp.y = pkh(r2, r3);
        *(uint2*)((char*)&hxch[dir][par][wc][qp * 16 + ln] + boff) = hp;
        float p = r0 * wnl.x + r1 * wnl.y + r2 * wnl.z + r3 * wnl.w;
        unsigned int pa = __builtin_bit_cast(unsigned int, p), pb = pa;
        pl32swap(pa, pb);
        float ps = __builtin_bit_cast(float, pa) + __builtin_bit_cast(float, pb);
        unsigned int pc = __builtin_bit_cast(unsigned int, ps), pd = pc;
        pl16swap(pc, pd);
        float ptot = __builtin_bit_cast(float, pc) + __builtin_bit_cast(float, pd);
        if (l < 16) accp[t] = ptot;
        asm volatile("s_waitcnt lgkmcnt(0)" ::: "memory");
        __builtin_amdgcn_sched_barrier(0);
        __builtin_amdgcn_s_barrier();
        __builtin_amdgcn_sched_barrier(0);
        #pragma unroll
        for (int c = 0; c < 4; ++c)
            hf[c] = __builtin_bit_cast(half8, hxch[dir][par][c][l]);
    };

    ld(x0, 0); ld(x1, 1); ld(x2, 2); ld(x3, 3);
    for (int c = 0; c < T / 4 - 1; ++c) {
        int i0 = c * 4;
        step(x0, i0);     ld(x0, i0 + 4);
        step(x1, i0 + 1); ld(x1, i0 + 5);
        step(x2, i0 + 2); ld(x2, i0 + 6);
        step(x3, i0 + 3); ld(x3, i0 + 7);
    }
    step(x0, T - 4);
    step(x1, T - 3);
    step(x2, T - 2);
    step(x3, T - 1);

    // in-block final: both dirs' partials were produced by THIS block
    __syncthreads();   // drains vmcnt -> partial stores visible via L2
    for (int idx = tid; idx < 16 * T; idx += 1024) {
        int bb = b0 + idx / T;
        int tt = idx - (idx / T) * T;
        size_t o = (size_t)bb * T + tt;
        float s = statd[bb];
        #pragma unroll
        for (int w = 0; w < 8; ++w)
            s += accf[(size_t)w * BT + o] + accb[(size_t)w * BT + o];
        out[o] = fmaxf(s, 0.f);
    }
}

extern "C" void kernel_launch(void* const* d_in, const int* in_sizes, int n_in,
                              void* d_out, int out_size, void* d_ws, size_t ws_size,
                              hipStream_t stream)
{
    const float* x_static  = (const float*)d_in[0];
    const float* x_dynamic = (const float*)d_in[1];
    const int*   norder    = (const int*)d_in[2];
    const float* w_s1   = (const float*)d_in[3];
    const float* b_s1   = (const float*)d_in[4];
    const float* w_s2   = (const float*)d_in[5];
    const float* b_s2   = (const float*)d_in[6];
    const float* w_dyn  = (const float*)d_in[7];
    const float* b_dyn  = (const float*)d_in[8];
    const float* w_ih_f = (const float*)d_in[9];
    const float* w_hh_f = (const float*)d_in[10];
    const float* b_ih_f = (const float*)d_in[11];
    const float* b_hh_f = (const float*)d_in[12];
    const float* w_ih_b = (const float*)d_in[13];
    const float* w_hh_b = (const float*)d_in[14];
    const float* b_ih_b = (const float*)d_in[15];
    const float* b_hh_b = (const float*)d_in[16];
    const float* nw     = (const float*)d_in[17];
    const float* nb     = (const float*)d_in[18];
    float* out = (float*)d_out;

    // ws: statd 2KB | accf 8*BT*4 | accb 8*BT*4 | xw 52.4MB | prepped wts
    char* ws = (char*)d_ws;
    float* statd = (float*)ws;
    float* accf  = (float*)(ws + 2048);
    float* accb  = (float*)(ws + 2048 + (size_t)8 * BT * 4);
    unsigned short* xw = (unsigned short*)(ws + 2048 + (size_t)16 * BT * 4);
    size_t xw_bytes = (size_t)2 * BT * HD * 2;   // 52.4 MB
    unsigned short* wdyn_bf = (unsigned short*)(ws + 2048 + (size_t)16 * BT * 4 + xw_bytes);
    unsigned short* wih_bf  = wdyn_bf + HD * 96;
    unsigned short* whh_h   = wih_bf + 2 * HD * HD;
    float* bsum = (float*)(whh_h + 2 * HD * HD);

    hipLaunchKernelGGL(k_prep_static, dim3(512), dim3(256), 0, stream,
                       w_dyn, w_ih_f, w_ih_b, w_hh_f, w_hh_b,
                       b_ih_f, b_hh_f, b_ih_b, b_hh_b,
                       wdyn_bf, wih_bf, whh_h, bsum,
                       x_static, w_s1, b_s1, w_s2, b_s2, norder, nw, nb,
                       statd);
    hipLaunchKernelGGL(k_dxw, dim3(256), dim3(256), 0, stream,
                       x_dynamic, wdyn_bf, b_dyn, wih_bf, bsum, xw);
    hipLaunchKernelGGL(k_scan_final, dim3(32), dim3(1024), 0, stream,
                       xw, whh_h, norder, nw, accf, accb, statd, out);
}